// Round 1
// baseline (1211.839 us; speedup 1.0000x reference)
//
#include <hip/hip_runtime.h>
#include <math.h>

// ---------------------------------------------------------------------------
// Problem constants: B=8, N=1024, DIM=768, H=12, dh=64 -> M=8192, EQKV=2304
// qkv[b,n, h*192 + {0:q, 64:k, 128:v} + d]
// ---------------------------------------------------------------------------

#define BK 16

// C[M x Ndim] = A[M x K] * W[Ndim x K]^T (+ bias), all row-major, NT layout.
template<bool BIAS>
__global__ __launch_bounds__(256, 3)
void gemm_nt(const float* __restrict__ A, const float* __restrict__ W,
             const float* __restrict__ bias, float* __restrict__ C,
             int Ndim, int K)
{
  __shared__ float As[BK][132];   // staged transposed: As[k][m]
  __shared__ float Bs[BK][132];   // Bs[k][n]

  const int tid = threadIdx.x;
  const int rg = tid >> 4;        // 0..15 row group
  const int cg = tid & 15;        // 0..15 col group

  const int bm = blockIdx.x * 128;
  const int bn = blockIdx.y * 128;

  const int lrow = tid >> 1;          // 0..127
  const int lk   = (tid & 1) * 8;     // 0 or 8

  const float* Ap = A + (size_t)(bm + lrow) * K + lk;
  const float* Wp = W + (size_t)(bn + lrow) * K + lk;

  float acc[8][8];
#pragma unroll
  for (int i = 0; i < 8; ++i)
#pragma unroll
    for (int j = 0; j < 8; ++j) acc[i][j] = 0.f;

  // prefetch first K-slab into registers
  float4 a0 = *(const float4*)(Ap + 0);
  float4 a1 = *(const float4*)(Ap + 4);
  float4 w0 = *(const float4*)(Wp + 0);
  float4 w1 = *(const float4*)(Wp + 4);

  for (int k0 = 0;;) {
    __syncthreads();   // previous compute done reading LDS
    As[lk+0][lrow]=a0.x; As[lk+1][lrow]=a0.y; As[lk+2][lrow]=a0.z; As[lk+3][lrow]=a0.w;
    As[lk+4][lrow]=a1.x; As[lk+5][lrow]=a1.y; As[lk+6][lrow]=a1.z; As[lk+7][lrow]=a1.w;
    Bs[lk+0][lrow]=w0.x; Bs[lk+1][lrow]=w0.y; Bs[lk+2][lrow]=w0.z; Bs[lk+3][lrow]=w0.w;
    Bs[lk+4][lrow]=w1.x; Bs[lk+5][lrow]=w1.y; Bs[lk+6][lrow]=w1.z; Bs[lk+7][lrow]=w1.w;
    __syncthreads();

    const int kn = k0 + BK;
    const bool more = kn < K;
    if (more) {          // register prefetch of next slab overlaps compute
      a0 = *(const float4*)(Ap + kn);
      a1 = *(const float4*)(Ap + kn + 4);
      w0 = *(const float4*)(Wp + kn);
      w1 = *(const float4*)(Wp + kn + 4);
    }

#pragma unroll
    for (int kk = 0; kk < BK; ++kk) {
      float4 x0 = *(const float4*)&As[kk][rg*4];
      float4 x1 = *(const float4*)&As[kk][rg*4 + 64];
      float4 y0 = *(const float4*)&Bs[kk][cg*4];
      float4 y1 = *(const float4*)&Bs[kk][cg*4 + 64];
      float xa[8] = {x0.x,x0.y,x0.z,x0.w, x1.x,x1.y,x1.z,x1.w};
      float yb[8] = {y0.x,y0.y,y0.z,y0.w, y1.x,y1.y,y1.z,y1.w};
#pragma unroll
      for (int i = 0; i < 8; ++i)
#pragma unroll
        for (int j = 0; j < 8; ++j)
          acc[i][j] = fmaf(xa[i], yb[j], acc[i][j]);
    }
    if (!more) break;
    k0 = kn;
  }

  // epilogue
  float bv[8];
  if (BIAS) {
    float4 b0 = *(const float4*)(bias + bn + cg*4);
    float4 b1 = *(const float4*)(bias + bn + 64 + cg*4);
    bv[0]=b0.x; bv[1]=b0.y; bv[2]=b0.z; bv[3]=b0.w;
    bv[4]=b1.x; bv[5]=b1.y; bv[6]=b1.z; bv[7]=b1.w;
  }
#pragma unroll
  for (int i = 0; i < 8; ++i) {
    const int m = bm + ((i < 4) ? (rg*4 + i) : (64 + rg*4 + (i - 4)));
    float* Cp = C + (size_t)m * Ndim + bn;
    float4 v0, v1;
    v0.x = acc[i][0]; v0.y = acc[i][1]; v0.z = acc[i][2]; v0.w = acc[i][3];
    v1.x = acc[i][4]; v1.y = acc[i][5]; v1.z = acc[i][6]; v1.w = acc[i][7];
    if (BIAS) {
      v0.x += bv[0]; v0.y += bv[1]; v0.z += bv[2]; v0.w += bv[3];
      v1.x += bv[4]; v1.y += bv[5]; v1.z += bv[6]; v1.w += bv[7];
    }
    *(float4*)(Cp + cg*4)      = v0;
    *(float4*)(Cp + 64 + cg*4) = v1;
  }
}

// ---------------------------------------------------------------------------
// Flash-style attention: one block = (b, h, 64 q-rows). Online softmax.
// scores = 8 * q.k (reference MULTIPLIES by sqrt(dh)).
// out written merged-heads: att[b, n, h*64 + d]
// ---------------------------------------------------------------------------
__global__ __launch_bounds__(256, 2)
void attn64(const float* __restrict__ qkv, float* __restrict__ out)
{
  __shared__ float Qt[64][68];   // Q^T [d][r]
  __shared__ float Kt[64][68];   // K^T [d][c]
  __shared__ float Vs[64][68];   // V   [k][d]
  __shared__ float Pt[64][68];   // P^T [k][r]

  const int tid = threadIdx.x;
  const int rg = tid >> 4, cg = tid & 15;
  const int r0 = rg * 4, c0 = cg * 4;

  const int qt = blockIdx.x;     // 0..15 q-tile
  const int bh = blockIdx.y;     // 0..95
  const int b = bh / 12, h = bh - b * 12;

  const float* qkvb = qkv + (size_t)b * 1024 * 2304 + h * 192;

  {
    const int row = tid >> 2;          // 0..63
    const int d0  = (tid & 3) * 16;
    const float* qp = qkvb + (size_t)(qt * 64 + row) * 2304 + d0;
#pragma unroll
    for (int t = 0; t < 4; ++t) {
      float4 v = *(const float4*)(qp + t * 4);
      Qt[d0 + t*4 + 0][row] = v.x;
      Qt[d0 + t*4 + 1][row] = v.y;
      Qt[d0 + t*4 + 2][row] = v.z;
      Qt[d0 + t*4 + 3][row] = v.w;
    }
  }

  float mrun[4], lrun[4], O[4][4];
#pragma unroll
  for (int i = 0; i < 4; ++i) {
    mrun[i] = -INFINITY; lrun[i] = 0.f;
#pragma unroll
    for (int j = 0; j < 4; ++j) O[i][j] = 0.f;
  }

  for (int kt = 0; kt < 16; ++kt) {
    __syncthreads();               // prev PV done with Kt/Vs/Pt (also fences Qt store, iter 0)
    {
      const int row = tid >> 2;
      const int d0  = (tid & 3) * 16;
      const float* kp = qkvb + (size_t)(kt * 64 + row) * 2304 + 64 + d0;
#pragma unroll
      for (int t = 0; t < 4; ++t) {
        float4 kv = *(const float4*)(kp + t * 4);
        Kt[d0 + t*4 + 0][row] = kv.x;
        Kt[d0 + t*4 + 1][row] = kv.y;
        Kt[d0 + t*4 + 2][row] = kv.z;
        Kt[d0 + t*4 + 3][row] = kv.w;
        float4 vv = *(const float4*)(kp + 64 + t * 4);   // v = k + 64
        *(float4*)&Vs[row][d0 + t*4] = vv;
      }
    }
    __syncthreads();

    // S = 8 * Q K^T   (4x4 per thread, in registers)
    float S[4][4];
#pragma unroll
    for (int i = 0; i < 4; ++i)
#pragma unroll
      for (int j = 0; j < 4; ++j) S[i][j] = 0.f;

#pragma unroll 8
    for (int d = 0; d < 64; ++d) {
      float4 qv = *(const float4*)&Qt[d][r0];
      float4 kv = *(const float4*)&Kt[d][c0];
      float qa[4] = {qv.x, qv.y, qv.z, qv.w};
      float ka[4] = {kv.x, kv.y, kv.z, kv.w};
#pragma unroll
      for (int i = 0; i < 4; ++i)
#pragma unroll
        for (int j = 0; j < 4; ++j)
          S[i][j] = fmaf(qa[i], ka[j], S[i][j]);
    }

    float P[4][4], tmax[4], rsum[4];
#pragma unroll
    for (int i = 0; i < 4; ++i) {
      S[i][0] *= 8.f; S[i][1] *= 8.f; S[i][2] *= 8.f; S[i][3] *= 8.f;
      tmax[i] = fmaxf(fmaxf(S[i][0], S[i][1]), fmaxf(S[i][2], S[i][3]));
    }
#pragma unroll
    for (int off = 1; off < 16; off <<= 1)
#pragma unroll
      for (int i = 0; i < 4; ++i)
        tmax[i] = fmaxf(tmax[i], __shfl_xor(tmax[i], off));

#pragma unroll
    for (int i = 0; i < 4; ++i) {
      const float mn = fmaxf(mrun[i], tmax[i]);
      const float al = __expf(mrun[i] - mn);   // 0 on first tile (-inf arg)
      mrun[i] = mn;
      rsum[i] = 0.f;
#pragma unroll
      for (int j = 0; j < 4; ++j) {
        P[i][j] = __expf(S[i][j] - mn);
        rsum[i] += P[i][j];
      }
      lrun[i] *= al;
#pragma unroll
      for (int j = 0; j < 4; ++j) O[i][j] *= al;
    }
#pragma unroll
    for (int off = 1; off < 16; off <<= 1)
#pragma unroll
      for (int i = 0; i < 4; ++i)
        rsum[i] += __shfl_xor(rsum[i], off);
#pragma unroll
    for (int i = 0; i < 4; ++i) lrun[i] += rsum[i];

    // P^T -> LDS for the PV outer product
#pragma unroll
    for (int i = 0; i < 4; ++i)
#pragma unroll
      for (int j = 0; j < 4; ++j)
        Pt[c0 + j][r0 + i] = P[i][j];

    __syncthreads();

    // O += P V
#pragma unroll 8
    for (int k = 0; k < 64; ++k) {
      float4 pv = *(const float4*)&Pt[k][r0];
      float4 vv = *(const float4*)&Vs[k][c0];
      float pa[4] = {pv.x, pv.y, pv.z, pv.w};
      float va[4] = {vv.x, vv.y, vv.z, vv.w};
#pragma unroll
      for (int i = 0; i < 4; ++i)
#pragma unroll
        for (int j = 0; j < 4; ++j)
          O[i][j] = fmaf(pa[i], va[j], O[i][j]);
    }
  }

  // normalize + write merged-heads layout [B, N, 768]
#pragma unroll
  for (int i = 0; i < 4; ++i) {
    const float inv = 1.f / lrun[i];
    float4 o;
    o.x = O[i][0]*inv; o.y = O[i][1]*inv; o.z = O[i][2]*inv; o.w = O[i][3]*inv;
    *(float4*)(out + ((size_t)b * 1024 + qt*64 + r0 + i) * 768 + h*64 + c0) = o;
  }
}

// ---------------------------------------------------------------------------

extern "C" void kernel_launch(void* const* d_in, const int* in_sizes, int n_in,
                              void* d_out, int out_size, void* d_ws, size_t ws_size,
                              hipStream_t stream)
{
  const float* img  = (const float*)d_in[0];   // [8,1024,768]
  const float* Wqkv = (const float*)d_in[1];   // [2304,768]
  const float* Wfc  = (const float*)d_in[2];   // [768,768]
  const float* bfc  = (const float*)d_in[3];   // [768]
  float* outp = (float*)d_out;                 // [8,1024,768]

  float* qkv = (float*)d_ws;                       // 8192*2304 f32 = 75.5 MB
  float* att = qkv + (size_t)8192 * 2304;          // 8192*768  f32 = 25.2 MB

  // 1) qkv = img @ Wqkv^T
  gemm_nt<false><<<dim3(64, 18), dim3(256), 0, stream>>>(img, Wqkv, nullptr, qkv, 2304, 768);
  // 2) attention per (b,h), 64 q-rows per block
  attn64<<<dim3(16, 96), dim3(256), 0, stream>>>(qkv, att);
  // 3) out = att @ Wfc^T + b
  gemm_nt<true><<<dim3(64, 6), dim3(256), 0, stream>>>(att, Wfc, bfc, outp, 768, 768);
}

// Round 2
// 387.357 us; speedup vs baseline: 3.1285x; 3.1285x over previous
//
#include <hip/hip_runtime.h>
#include <math.h>

// B=8, N=1024, DIM=768, H=12, dh=64 -> M=8192, EQKV=2304
// Split-precision bf16 path: x ~= bf2f(hi) + bf2f(lo); 3-MFMA emulated fp32 GEMM.

typedef __attribute__((ext_vector_type(8))) short short8;
typedef __attribute__((ext_vector_type(4))) float f32x4;

#define MFMA(a, b, c) __builtin_amdgcn_mfma_f32_16x16x32_bf16((a), (b), (c), 0, 0, 0)

__device__ __forceinline__ unsigned short f2bf(float x) {
  unsigned u = __builtin_bit_cast(unsigned, x);
  return (unsigned short)((u + 0x7FFFu + ((u >> 16) & 1u)) >> 16);
}
__device__ __forceinline__ float bf2f(unsigned short h) {
  unsigned u = ((unsigned)h) << 16;
  return __builtin_bit_cast(float, u);
}
__device__ __forceinline__ unsigned packsplit(float x) {
  unsigned short hi = f2bf(x);
  unsigned short lo = f2bf(x - bf2f(hi));
  return (((unsigned)hi) << 16) | (unsigned)lo;
}

// ---------------------------------------------------------------------------
// C[M x Ndim] = A[M x K] * W[Ndim x K]^T (+bias). A either fp32 or packed-u32
// (hi|lo bf16). Output either fp32 (+bias) or packed-u32.
// 128x128 tile, BK=32, 256 threads (4 waves, 2x2 of 64x64).
// ---------------------------------------------------------------------------
template <bool A_PACKED, bool STORE_PACKED, bool BIAS>
__global__ __launch_bounds__(256, 2)
void k_gemm(const void* __restrict__ Avoid, const float* __restrict__ W,
            const float* __restrict__ bias, void* __restrict__ Cvoid,
            int Ndim, int K)
{
  __shared__ __align__(16) short AsH[128][40];
  __shared__ __align__(16) short AsL[128][40];
  __shared__ __align__(16) short WsH[128][40];
  __shared__ __align__(16) short WsL[128][40];

  const int tid = threadIdx.x;
  const int lane = tid & 63;
  const int w = tid >> 6;
  const int wm = w >> 1, wn = w & 1;
  const int fr = lane & 15;
  const int fk = (lane >> 4) * 8;
  const int bm = blockIdx.x * 128, bn = blockIdx.y * 128;

  const int srow = tid >> 1;
  const int sk = (tid & 1) * 16;

  const float*    Apf = A_PACKED ? nullptr : ((const float*)Avoid) + (size_t)(bm + srow) * K + sk;
  const unsigned* Apu = A_PACKED ? ((const unsigned*)Avoid) + (size_t)(bm + srow) * K + sk : nullptr;
  const float*    Wp  = W + (size_t)(bn + srow) * K + sk;

  f32x4 acc[4][4];
#pragma unroll
  for (int i = 0; i < 4; ++i)
#pragma unroll
    for (int j = 0; j < 4; ++j) acc[i][j] = (f32x4){0.f, 0.f, 0.f, 0.f};

  float4 ra[4], rw[4];
  uint4  pa[4];

  auto LOAD = [&](int kt) {
    const int off = kt * 32;
#pragma unroll
    for (int q = 0; q < 4; ++q) {
      if constexpr (A_PACKED) pa[q] = *(const uint4*)(Apu + off + q * 4);
      else                    ra[q] = *(const float4*)(Apf + off + q * 4);
      rw[q] = *(const float4*)(Wp + off + q * 4);
    }
  };

  LOAD(0);
  const int nk = K / 32;
  for (int kt = 0; kt < nk; ++kt) {
    __syncthreads();
    // ---- convert + stage to LDS ----
#pragma unroll
    for (int hh = 0; hh < 2; ++hh) {
      short8 vh, vl;
      if constexpr (A_PACKED) {
        unsigned u[8] = {pa[2*hh].x, pa[2*hh].y, pa[2*hh].z, pa[2*hh].w,
                         pa[2*hh+1].x, pa[2*hh+1].y, pa[2*hh+1].z, pa[2*hh+1].w};
#pragma unroll
        for (int e = 0; e < 8; ++e) { vh[e] = (short)(u[e] >> 16); vl[e] = (short)(u[e] & 0xffffu); }
      } else {
        float x[8] = {ra[2*hh].x, ra[2*hh].y, ra[2*hh].z, ra[2*hh].w,
                      ra[2*hh+1].x, ra[2*hh+1].y, ra[2*hh+1].z, ra[2*hh+1].w};
#pragma unroll
        for (int e = 0; e < 8; ++e) {
          unsigned short hi = f2bf(x[e]);
          vh[e] = (short)hi;
          vl[e] = (short)f2bf(x[e] - bf2f(hi));
        }
      }
      *(short8*)&AsH[srow][sk + 8*hh] = vh;
      *(short8*)&AsL[srow][sk + 8*hh] = vl;

      short8 wh, wl;
      float y[8] = {rw[2*hh].x, rw[2*hh].y, rw[2*hh].z, rw[2*hh].w,
                    rw[2*hh+1].x, rw[2*hh+1].y, rw[2*hh+1].z, rw[2*hh+1].w};
#pragma unroll
      for (int e = 0; e < 8; ++e) {
        unsigned short hi = f2bf(y[e]);
        wh[e] = (short)hi;
        wl[e] = (short)f2bf(y[e] - bf2f(hi));
      }
      *(short8*)&WsH[srow][sk + 8*hh] = wh;
      *(short8*)&WsL[srow][sk + 8*hh] = wl;
    }
    __syncthreads();

    if (kt + 1 < nk) LOAD(kt + 1);   // prefetch next slab during compute

    // ---- fragments + 48 MFMA ----
    short8 aH[4], aL[4], bH[4], bL[4];
#pragma unroll
    for (int i = 0; i < 4; ++i) {
      aH[i] = *(const short8*)&AsH[wm*64 + i*16 + fr][fk];
      aL[i] = *(const short8*)&AsL[wm*64 + i*16 + fr][fk];
      bH[i] = *(const short8*)&WsH[wn*64 + i*16 + fr][fk];
      bL[i] = *(const short8*)&WsL[wn*64 + i*16 + fr][fk];
    }
#pragma unroll
    for (int i = 0; i < 4; ++i)
#pragma unroll
      for (int j = 0; j < 4; ++j) {
        acc[i][j] = MFMA(aH[i], bH[j], acc[i][j]);
        acc[i][j] = MFMA(aH[i], bL[j], acc[i][j]);
        acc[i][j] = MFMA(aL[i], bH[j], acc[i][j]);
      }
  }

  // ---- epilogue ----
  const int row0 = bm + wm * 64 + (lane >> 4) * 4;
  const int col0 = bn + wn * 64 + fr;
  if constexpr (STORE_PACKED) {
    unsigned* Cp = (unsigned*)Cvoid;
#pragma unroll
    for (int i = 0; i < 4; ++i)
#pragma unroll
      for (int j = 0; j < 4; ++j) {
        const int row = row0 + i * 16;
        const int col = col0 + j * 16;
#pragma unroll
        for (int r = 0; r < 4; ++r)
          Cp[(size_t)(row + r) * Ndim + col] = packsplit(acc[i][j][r]);
      }
  } else {
    float* Cp = (float*)Cvoid;
    float bj[4] = {0.f, 0.f, 0.f, 0.f};
    if constexpr (BIAS) {
#pragma unroll
      for (int j = 0; j < 4; ++j) bj[j] = bias[col0 + j * 16];
    }
#pragma unroll
    for (int i = 0; i < 4; ++i)
#pragma unroll
      for (int j = 0; j < 4; ++j) {
        const int row = row0 + i * 16;
        const int col = col0 + j * 16;
#pragma unroll
        for (int r = 0; r < 4; ++r)
          Cp[(size_t)(row + r) * Ndim + col] = acc[i][j][r] + bj[j];
      }
  }
}

// ---------------------------------------------------------------------------
// Flash attention, split-bf16 MFMA. Block = 512 thr (8 waves), q-tile 128
// (16 rows/wave), KV tiles of 64. qkvP packed u32 (hi|lo). scores = 8*(q.k).
// Output attP packed u32, merged heads [B*N][768].
// ---------------------------------------------------------------------------
__global__ __launch_bounds__(512, 2)
void k_attn(const unsigned* __restrict__ qkvP, unsigned* __restrict__ attP)
{
  __shared__ __align__(16) short KsH[64][72];
  __shared__ __align__(16) short KsL[64][72];
  __shared__ __align__(16) short VtH[64][72];
  __shared__ __align__(16) short VtL[64][72];
  __shared__ __align__(16) short PsH[8][16][72];
  __shared__ __align__(16) short PsL[8][16][72];

  const int tid = threadIdx.x, lane = tid & 63, w = tid >> 6;
  const int fr = lane & 15, fk = (lane >> 4) * 8;
  const int qt = blockIdx.x, bh = blockIdx.y;
  const int b = bh / 12, h = bh - b * 12;
  const unsigned* base = qkvP + (size_t)b * 1024 * 2304 + (size_t)h * 192;

  // Q fragments, held in registers across all KV tiles
  short8 qH[2], qL[2];
  {
    const unsigned* qp = base + (size_t)(qt * 128 + w * 16 + fr) * 2304;
#pragma unroll
    for (int ks = 0; ks < 2; ++ks) {
      uint4 u0 = *(const uint4*)(qp + 32 * ks + fk);
      uint4 u1 = *(const uint4*)(qp + 32 * ks + fk + 4);
      unsigned uu[8] = {u0.x, u0.y, u0.z, u0.w, u1.x, u1.y, u1.z, u1.w};
#pragma unroll
      for (int e = 0; e < 8; ++e) {
        qH[ks][e] = (short)(uu[e] >> 16);
        qL[ks][e] = (short)(uu[e] & 0xffffu);
      }
    }
  }

  f32x4 O[4];
  float mrun[4], lrun[4];
#pragma unroll
  for (int r = 0; r < 4; ++r) { mrun[r] = -INFINITY; lrun[r] = 0.f; }
#pragma unroll
  for (int nf = 0; nf < 4; ++nf) O[nf] = (f32x4){0.f, 0.f, 0.f, 0.f};

  const int skv = tid & 63;
  const int sd  = (tid >> 6) * 8;
  const unsigned* kvbase = base + 64 + sd;

  for (int kt = 0; kt < 16; ++kt) {
    __syncthreads();
    // ---- stage K (row-major) and V (transposed), hi/lo ----
    {
      const unsigned* kp = kvbase + (size_t)(kt * 64 + skv) * 2304;
      uint4 ku0 = *(const uint4*)(kp);
      uint4 ku1 = *(const uint4*)(kp + 4);
      uint4 vu0 = *(const uint4*)(kp + 64);
      uint4 vu1 = *(const uint4*)(kp + 68);
      unsigned ka[8] = {ku0.x, ku0.y, ku0.z, ku0.w, ku1.x, ku1.y, ku1.z, ku1.w};
      short8 kh, kl;
#pragma unroll
      for (int e = 0; e < 8; ++e) { kh[e] = (short)(ka[e] >> 16); kl[e] = (short)(ka[e] & 0xffffu); }
      *(short8*)&KsH[skv][sd] = kh;
      *(short8*)&KsL[skv][sd] = kl;
      unsigned va[8] = {vu0.x, vu0.y, vu0.z, vu0.w, vu1.x, vu1.y, vu1.z, vu1.w};
#pragma unroll
      for (int e = 0; e < 8; ++e) {
        VtH[sd + e][skv] = (short)(va[e] >> 16);
        VtL[sd + e][skv] = (short)(va[e] & 0xffffu);
      }
    }
    __syncthreads();

    // ---- S = 8 * Q K^T (split 3-MFMA) ----
    f32x4 S[4];
#pragma unroll
    for (int nf = 0; nf < 4; ++nf) S[nf] = (f32x4){0.f, 0.f, 0.f, 0.f};
#pragma unroll
    for (int ks = 0; ks < 2; ++ks)
#pragma unroll
      for (int nf = 0; nf < 4; ++nf) {
        short8 kbh = *(const short8*)&KsH[nf * 16 + fr][fk + 32 * ks];
        short8 kbl = *(const short8*)&KsL[nf * 16 + fr][fk + 32 * ks];
        S[nf] = MFMA(qH[ks], kbh, S[nf]);
        S[nf] = MFMA(qH[ks], kbl, S[nf]);
        S[nf] = MFMA(qL[ks], kbh, S[nf]);
      }

    // ---- online softmax (rows live in D-layout: row=(lane>>4)*4+r) ----
    float tmax[4];
#pragma unroll
    for (int r = 0; r < 4; ++r) {
      float a = S[0][r] * 8.f, b2 = S[1][r] * 8.f, c = S[2][r] * 8.f, d = S[3][r] * 8.f;
      S[0][r] = a; S[1][r] = b2; S[2][r] = c; S[3][r] = d;
      tmax[r] = fmaxf(fmaxf(a, b2), fmaxf(c, d));
    }
#pragma unroll
    for (int off = 1; off < 16; off <<= 1)
#pragma unroll
      for (int r = 0; r < 4; ++r) tmax[r] = fmaxf(tmax[r], __shfl_xor(tmax[r], off));

    float Pv[4][4], rsum[4], al[4];
#pragma unroll
    for (int r = 0; r < 4; ++r) {
      float mn = fmaxf(mrun[r], tmax[r]);
      al[r] = __expf(mrun[r] - mn);
      mrun[r] = mn;
      rsum[r] = 0.f;
#pragma unroll
      for (int nf = 0; nf < 4; ++nf) {
        float p = __expf(S[nf][r] - mn);
        Pv[nf][r] = p;
        rsum[r] += p;
      }
    }
#pragma unroll
    for (int off = 1; off < 16; off <<= 1)
#pragma unroll
      for (int r = 0; r < 4; ++r) rsum[r] += __shfl_xor(rsum[r], off);
#pragma unroll
    for (int r = 0; r < 4; ++r) lrun[r] = lrun[r] * al[r] + rsum[r];
#pragma unroll
    for (int nf = 0; nf < 4; ++nf) {
#pragma unroll
      for (int r = 0; r < 4; ++r) O[nf][r] *= al[r];
    }

    // ---- P -> per-wave LDS (hi/lo split) ----
    const int pr = (lane >> 4) * 4;
#pragma unroll
    for (int nf = 0; nf < 4; ++nf)
#pragma unroll
      for (int r = 0; r < 4; ++r) {
        unsigned short ph = f2bf(Pv[nf][r]);
        unsigned short pl = f2bf(Pv[nf][r] - bf2f(ph));
        PsH[w][pr + r][nf * 16 + fr] = (short)ph;
        PsL[w][pr + r][nf * 16 + fr] = (short)pl;
      }

    // ---- O += P V (split 3-MFMA) ----
#pragma unroll
    for (int ks = 0; ks < 2; ++ks) {
      short8 paH = *(const short8*)&PsH[w][fr][fk + 32 * ks];
      short8 paL = *(const short8*)&PsL[w][fr][fk + 32 * ks];
#pragma unroll
      for (int nf = 0; nf < 4; ++nf) {
        short8 vbH = *(const short8*)&VtH[nf * 16 + fr][fk + 32 * ks];
        short8 vbL = *(const short8*)&VtL[nf * 16 + fr][fk + 32 * ks];
        O[nf] = MFMA(paH, vbH, O[nf]);
        O[nf] = MFMA(paH, vbL, O[nf]);
        O[nf] = MFMA(paL, vbH, O[nf]);
      }
    }
  }

  // ---- normalize + packed store, merged heads ----
  {
    unsigned* op = attP + (size_t)(b * 1024 + qt * 128 + w * 16 + (lane >> 4) * 4) * 768 + h * 64 + fr;
#pragma unroll
    for (int r = 0; r < 4; ++r) {
      float inv = 1.f / lrun[r];
#pragma unroll
      for (int nf = 0; nf < 4; ++nf)
        op[(size_t)r * 768 + nf * 16] = packsplit(O[nf][r] * inv);
    }
  }
}

// ---------------------------------------------------------------------------

extern "C" void kernel_launch(void* const* d_in, const int* in_sizes, int n_in,
                              void* d_out, int out_size, void* d_ws, size_t ws_size,
                              hipStream_t stream)
{
  const float* img  = (const float*)d_in[0];   // [8,1024,768]
  const float* Wqkv = (const float*)d_in[1];   // [2304,768]
  const float* Wfc  = (const float*)d_in[2];   // [768,768]
  const float* bfc  = (const float*)d_in[3];   // [768]
  float* outp = (float*)d_out;                 // [8,1024,768] fp32

  unsigned* qkvP = (unsigned*)d_ws;                        // 8192*2304 u32 = 75.5 MB
  unsigned* attP = qkvP + (size_t)8192 * 2304;             // 8192*768  u32 = 25.2 MB

  // 1) qkv = img @ Wqkv^T  (fp32 in, packed hi/lo out)
  k_gemm<false, true, false><<<dim3(64, 18), dim3(256), 0, stream>>>(
      (const void*)img, Wqkv, nullptr, (void*)qkvP, 2304, 768);
  // 2) flash attention (packed in, packed out)
  k_attn<<<dim3(8, 96), dim3(512), 0, stream>>>(qkvP, attP);
  // 3) out = att @ Wfc^T + b  (packed in, fp32 out)
  k_gemm<true, false, true><<<dim3(64, 6), dim3(256), 0, stream>>>(
      (const void*)attP, Wfc, bfc, (void*)outp, 768, 768);
}